// Round 1
// baseline (167.483 us; speedup 1.0000x reference)
//
#include <hip/hip_runtime.h>

typedef __attribute__((ext_vector_type(8))) short bf16x8;
typedef __attribute__((ext_vector_type(4))) float f32x4;
typedef unsigned short u16;

constexpr int N = 8192;
constexpr int D = 128;
constexpr float CEXP   = 2.8853900817779268f;  // log2(e)/tau, tau = 0.5
constexpr float BSCALE = 1.6986435688113073f;  // sqrt(CEXP) folded into bf16 inputs

// ---------- fp32 -> bf16 (pre-scaled) ----------
__device__ __forceinline__ u16 f2bf(float x) {
  union { float f; unsigned u; } v;
  v.f = x;
  unsigned r = v.u + 0x7fffu + ((v.u >> 16) & 1u);  // RNE
  return (u16)(r >> 16);
}

__global__ void convert_kernel(const float4* __restrict__ z1, const float4* __restrict__ z2,
                               uint2* __restrict__ o1, uint2* __restrict__ o2) {
  int t = blockIdx.x * 256 + threadIdx.x;  // N*D/4 = 262144 float4s per matrix
  float4 a = z1[t];
  float4 b = z2[t];
  uint2 pa, pb;
  pa.x = (unsigned)f2bf(a.x * BSCALE) | ((unsigned)f2bf(a.y * BSCALE) << 16);
  pa.y = (unsigned)f2bf(a.z * BSCALE) | ((unsigned)f2bf(a.w * BSCALE) << 16);
  pb.x = (unsigned)f2bf(b.x * BSCALE) | ((unsigned)f2bf(b.y * BSCALE) << 16);
  pb.y = (unsigned)f2bf(b.z * BSCALE) | ((unsigned)f2bf(b.w * BSCALE) << 16);
  o1[t] = pa;
  o2[t] = pb;
}

// ---------- zero accumulators (ws is poisoned 0xAA, not re-poisoned between replays) ----------
__global__ void zero_kernel(float* __restrict__ p) {
  p[blockIdx.x * 256 + threadIdx.x] = 0.0f;  // grid covers 3*N floats
}

// ---------- GEMM + exp + row/col sums ----------
// LDS tile: 128 rows x 256B (bf16[128]), XOR-swizzled: byte_off ^= (row&7)<<4
__device__ __forceinline__ void load_tile(char* __restrict__ lds, const u16* __restrict__ src, int tid) {
  // whole tile is 32KB contiguous in global (full-width rows)
#pragma unroll
  for (int c = 0; c < 8; ++c) {
    int chunk = c * 256 + tid;       // 2048 chunks of 16B
    int r  = chunk >> 4;             // row 0..127
    int co = chunk & 15;             // 16B chunk within row
    int4 v = *(const int4*)(src + r * D + co * 8);
    *(int4*)(lds + r * 256 + ((co << 4) ^ ((r & 7) << 4))) = v;
  }
}

__device__ __forceinline__ void zero_acc(f32x4 (&acc)[4][4]) {
#pragma unroll
  for (int m = 0; m < 4; ++m)
#pragma unroll
    for (int n = 0; n < 4; ++n) acc[m][n] = f32x4{0.f, 0.f, 0.f, 0.f};
}

__device__ __forceinline__ void mfma_tile(f32x4 (&acc)[4][4], const char* __restrict__ Ab,
                                          const char* __restrict__ Bb, int l, int wr, int wc) {
  const int lr = l & 15;
  const int lg = l >> 4;
#pragma unroll
  for (int kk = 0; kk < 4; ++kk) {
    bf16x8 af[4], bfr[4];
    const int boff = kk * 64 + (lg << 4);
#pragma unroll
    for (int m = 0; m < 4; ++m) {
      int row = wr * 64 + m * 16 + lr;
      af[m] = *(const bf16x8*)(Ab + row * 256 + (boff ^ ((row & 7) << 4)));
    }
#pragma unroll
    for (int n = 0; n < 4; ++n) {
      int row = wc * 64 + n * 16 + lr;
      bfr[n] = *(const bf16x8*)(Bb + row * 256 + (boff ^ ((row & 7) << 4)));
    }
#pragma unroll
    for (int m = 0; m < 4; ++m)
#pragma unroll
      for (int n = 0; n < 4; ++n)
        acc[m][n] = __builtin_amdgcn_mfma_f32_16x16x32_bf16(af[m], bfr[n], acc[m][n], 0, 0, 0);
  }
}

// exp2(acc) then reduce: rows across the 16 col-lanes, cols across regs + lane-groups.
// C/D layout (measured): col = lane&15, row = (lane>>4)*4 + reg.
template <bool COLS>
__device__ __forceinline__ void reduce_tile(const f32x4 (&acc)[4][4], float* __restrict__ rowsum,
                                            float* __restrict__ colsum, int l) {
  float rowp[4][4];
  float colp[4];
#pragma unroll
  for (int m = 0; m < 4; ++m)
#pragma unroll
    for (int r = 0; r < 4; ++r) rowp[m][r] = 0.f;
#pragma unroll
  for (int n = 0; n < 4; ++n) colp[n] = 0.f;

#pragma unroll
  for (int m = 0; m < 4; ++m) {
#pragma unroll
    for (int n = 0; n < 4; ++n) {
      float v0 = exp2f(acc[m][n][0]);
      float v1 = exp2f(acc[m][n][1]);
      float v2 = exp2f(acc[m][n][2]);
      float v3 = exp2f(acc[m][n][3]);
      rowp[m][0] += v0;
      rowp[m][1] += v1;
      rowp[m][2] += v2;
      rowp[m][3] += v3;
      if (COLS) colp[n] += (v0 + v1) + (v2 + v3);
    }
  }
#pragma unroll
  for (int m = 0; m < 4; ++m)
#pragma unroll
    for (int r = 0; r < 4; ++r) {
      float s = rowp[m][r];
      s += __shfl_xor(s, 1);
      s += __shfl_xor(s, 2);
      s += __shfl_xor(s, 4);
      s += __shfl_xor(s, 8);
      rowp[m][r] = s;
    }
  if ((l & 15) == 0) {
    int rg = (l >> 4) * 4;
#pragma unroll
    for (int m = 0; m < 4; ++m)
#pragma unroll
      for (int r = 0; r < 4; ++r) atomicAdd(&rowsum[m * 16 + rg + r], rowp[m][r]);
  }
  if (COLS) {
#pragma unroll
    for (int n = 0; n < 4; ++n) {
      float c = colp[n];
      c += __shfl_xor(c, 16);
      c += __shfl_xor(c, 32);
      colp[n] = c;
    }
    if (l < 16) {
#pragma unroll
      for (int n = 0; n < 4; ++n) atomicAdd(&colsum[n * 16 + l], colp[n]);
    }
  }
}

__global__ __launch_bounds__(256, 2) void gemm_kernel(const u16* __restrict__ z1b,
                                                      const u16* __restrict__ z2b,
                                                      float* __restrict__ rowRefl,
                                                      float* __restrict__ rowBet,
                                                      float* __restrict__ colBet) {
  __shared__ __align__(16) char Ab[128 * 256];
  __shared__ __align__(16) char Bb[128 * 256];
  const int tid = threadIdx.x;
  const int l = tid & 63;
  const int w = tid >> 6;
  const int wr = w >> 1;  // 2x2 wave grid, each 64x64
  const int wc = w & 1;
  const int bi = blockIdx.x >> 6;  // 64x64 tiles of 128^2
  const int bj = blockIdx.x & 63;

  load_tile(Ab, z1b + (size_t)bi * 128 * D, tid);
  load_tile(Bb, z1b + (size_t)bj * 128 * D, tid);
  __syncthreads();

  f32x4 acc[4][4];
  zero_acc(acc);
  mfma_tile(acc, Ab, Bb, l, wr, wc);   // refl = z1_I . z1_J^T (pre-scaled)
  __syncthreads();                      // all waves done reading Bb
  load_tile(Bb, z2b + (size_t)bj * 128 * D, tid);  // overlap with epilogue below
  reduce_tile<false>(acc, rowRefl + bi * 128 + wr * 64, nullptr, l);
  __syncthreads();                      // z2 tile visible
  zero_acc(acc);
  mfma_tile(acc, Ab, Bb, l, wr, wc);   // between = z1_I . z2_J^T
  reduce_tile<true>(acc, rowBet + bi * 128 + wr * 64, colBet + bj * 128 + wc * 64, l);
}

// ---------- per-row loss (exact fp32 diagonals) ----------
__global__ void row_loss_kernel(const float* __restrict__ z1, const float* __restrict__ z2,
                                const float* __restrict__ rowRefl, const float* __restrict__ rowBet,
                                const float* __restrict__ colBet, float* __restrict__ rowLoss) {
  int gt = blockIdx.x * blockDim.x + threadIdx.x;
  int w = gt >> 6;  // one wave per row
  int l = threadIdx.x & 63;
  if (w >= N) return;
  float a0 = z1[w * D + l], a1 = z1[w * D + 64 + l];
  float b0 = z2[w * D + l], b1 = z2[w * D + 64 + l];
  float d11 = a0 * a0 + a1 * a1;  // |z1_i|^2
  float d12 = a0 * b0 + a1 * b1;  // z1_i . z2_i
#pragma unroll
  for (int mask = 1; mask < 64; mask <<= 1) {
    d11 += __shfl_xor(d11, mask);
    d12 += __shfl_xor(d12, mask);
  }
  if (l == 0) {
    float rdiag = exp2f(d11 * CEXP);  // exp(|z1_i|^2 / tau), exact fp32
    float denom1 = rowRefl[w] - rdiag + rowBet[w];
    float denom2 = rowRefl[w] - rdiag + colBet[w];
    // -log(pos) = -d12/tau = -2*d12 exactly (no exp/log roundtrip)
    rowLoss[w] = 0.5f * (logf(denom1) + logf(denom2)) - 2.0f * d12;
  }
}

__global__ void final_reduce_kernel(const float* __restrict__ rowLoss, float* __restrict__ out) {
  __shared__ float sdata[256];
  float s = 0.f;
  for (int i = threadIdx.x; i < N; i += 256) s += rowLoss[i];
  sdata[threadIdx.x] = s;
  __syncthreads();
  for (int st = 128; st > 0; st >>= 1) {
    if ((int)threadIdx.x < st) sdata[threadIdx.x] += sdata[threadIdx.x + st];
    __syncthreads();
  }
  if (threadIdx.x == 0) out[0] = sdata[0] * (1.0f / (float)N);
}

extern "C" void kernel_launch(void* const* d_in, const int* in_sizes, int n_in,
                              void* d_out, int out_size, void* d_ws, size_t ws_size,
                              hipStream_t stream) {
  const float* z1 = (const float*)d_in[0];
  const float* z2 = (const float*)d_in[1];
  float* out = (float*)d_out;
  char* ws = (char*)d_ws;

  // workspace layout: z1b(2MB) | z2b(2MB) | rowRefl(32KB) | rowBet | colBet | rowLoss
  u16* z1b = (u16*)ws;
  u16* z2b = (u16*)(ws + (size_t)N * D * 2);
  float* rowRefl = (float*)(ws + (size_t)2 * N * D * 2);
  float* rowBet = rowRefl + N;
  float* colBet = rowBet + N;
  float* rowLoss = colBet + N;

  convert_kernel<<<(N * D / 4) / 256, 256, 0, stream>>>((const float4*)z1, (const float4*)z2,
                                                        (uint2*)z1b, (uint2*)z2b);
  zero_kernel<<<(3 * N) / 256, 256, 0, stream>>>(rowRefl);  // rowRefl, rowBet, colBet contiguous
  gemm_kernel<<<64 * 64, 256, 0, stream>>>(z1b, z2b, rowRefl, rowBet, colBet);
  row_loss_kernel<<<(N * 64) / 256, 256, 0, stream>>>(z1, z2, rowRefl, rowBet, colBet, rowLoss);
  final_reduce_kernel<<<1, 256, 0, stream>>>(rowLoss, out);
}

// Round 2
// 63.571 us; speedup vs baseline: 2.6346x; 2.6346x over previous
//
#include <hip/hip_runtime.h>

typedef __attribute__((ext_vector_type(8))) short bf16x8;
typedef __attribute__((ext_vector_type(4))) float f32x4;
typedef unsigned short u16;

constexpr int N = 8192;
constexpr int D = 128;
constexpr float CEXP   = 2.8853900817779268f;  // log2(e)/tau, tau = 0.5
constexpr float BSCALE = 1.6986435688113073f;  // sqrt(CEXP) folded into bf16 inputs

#if __has_builtin(__builtin_amdgcn_exp2f)
__device__ __forceinline__ float fexp2(float x) { return __builtin_amdgcn_exp2f(x); }
#else
__device__ __forceinline__ float fexp2(float x) { return exp2f(x); }
#endif

// ---------- fp32 -> bf16 (pre-scaled) ----------
__device__ __forceinline__ u16 f2bf(float x) {
  union { float f; unsigned u; } v;
  v.f = x;
  unsigned r = v.u + 0x7fffu + ((v.u >> 16) & 1u);  // RNE
  return (u16)(r >> 16);
}

__global__ void convert_kernel(const float4* __restrict__ z1, const float4* __restrict__ z2,
                               uint2* __restrict__ o1, uint2* __restrict__ o2) {
  int t = blockIdx.x * 256 + threadIdx.x;  // N*D/4 = 262144 float4s per matrix
  float4 a = z1[t];
  float4 b = z2[t];
  uint2 pa, pb;
  pa.x = (unsigned)f2bf(a.x * BSCALE) | ((unsigned)f2bf(a.y * BSCALE) << 16);
  pa.y = (unsigned)f2bf(a.z * BSCALE) | ((unsigned)f2bf(a.w * BSCALE) << 16);
  pb.x = (unsigned)f2bf(b.x * BSCALE) | ((unsigned)f2bf(b.y * BSCALE) << 16);
  pb.y = (unsigned)f2bf(b.z * BSCALE) | ((unsigned)f2bf(b.w * BSCALE) << 16);
  o1[t] = pa;
  o2[t] = pb;
}

// ---------- zero accumulators + output ----------
__global__ void zero_kernel(float* __restrict__ p, float* __restrict__ out) {
  int g = blockIdx.x * 256 + threadIdx.x;  // grid covers 3*N floats
  p[g] = 0.0f;
  if (g == 0) out[0] = 0.0f;
}

// ---------- async stage 32KB tile: linear LDS dest, pre-swizzled global src (m173) ----------
// Swizzled LDS layout: content of logical (row, chunk c) lives at byte row*256 + ((c ^ (row&15))<<4)
__device__ __forceinline__ void stage32k(char* lds, const char* gsrc, int soff, int doff) {
#pragma unroll
  for (int s = 0; s < 8; ++s) {
    __builtin_amdgcn_global_load_lds(
        (const __attribute__((address_space(1))) unsigned*)(gsrc + soff + s * 4096),
        (__attribute__((address_space(3))) unsigned*)(lds + doff + s * 4096), 16, 0, 0);
  }
}

// ---------- fused GEMM(z1_I x {z1,z2}_J^T) + exp + row/col sums ----------
// grid: 512 blocks = bi(64) x jg(8). jg<4: refl (B=z1, J tiles jg*16..+15, rowRefl).
// jg>=4: between (B=z2, rowBet + colBet). A held in registers across all 16 J tiles.
__global__ __launch_bounds__(256, 2) void gemm_kernel(const u16* __restrict__ z1b,
                                                      const u16* __restrict__ z2b,
                                                      float* __restrict__ rowRefl,
                                                      float* __restrict__ rowBet,
                                                      float* __restrict__ colBet) {
  __shared__ __align__(16) char B0[32768];
  __shared__ __align__(16) char B1[32768];
  const int tid = threadIdx.x;
  const int l = tid & 63, w = tid >> 6;
  const int wr = w >> 1, wc = w & 1;   // 2x2 wave grid over the 128x128 tile
  const int lr = l & 15, lg = l >> 4;
  const int bi = blockIdx.x >> 3, jg = blockIdx.x & 7;
  const bool between = (jg & 4) != 0;
  const u16* bsrc = between ? z2b : z1b;
  const int j0 = (jg & 3) * 16;

  // per-thread staging offsets (s=0; stride 4096 per s)
  const int soff = (tid >> 4) * 256 + (((tid & 15) ^ (tid >> 4)) << 4);  // swizzled global src
  const int doff = tid * 16;                                             // linear LDS dest

  // ---- load A tile into registers (via LDS) ----
  stage32k(B0, (const char*)(z1b + (size_t)bi * 128 * D), soff, doff);
  __syncthreads();
  bf16x8 af[4][4];  // [m][kk]
#pragma unroll
  for (int m = 0; m < 4; ++m) {
    const int row = wr * 64 + m * 16 + lr;
#pragma unroll
    for (int kk = 0; kk < 4; ++kk)
      af[m][kk] = *(const bf16x8*)(B0 + row * 256 + (((kk * 4 + lg) ^ lr) << 4));
  }
  __syncthreads();  // all waves done reading B0

  stage32k(B0, (const char*)(bsrc + (size_t)j0 * 128 * D), soff, doff);  // prologue: tile 0

  float rowp[4][4];
#pragma unroll
  for (int m = 0; m < 4; ++m)
#pragma unroll
    for (int r = 0; r < 4; ++r) rowp[m][r] = 0.f;

  for (int t = 0; t < 16; ++t) {
    __syncthreads();  // tile t staged (vmcnt drained by barrier); buf(t+1)'s readers done
    const char* cur = (t & 1) ? B1 : B0;
    char* nxt = (t & 1) ? B0 : B1;
    if (t + 1 < 16)
      stage32k(nxt, (const char*)(bsrc + (size_t)(j0 + t + 1) * 128 * D), soff, doff);

    f32x4 acc[4][4];
    const f32x4 z4 = {0.f, 0.f, 0.f, 0.f};
    {
      bf16x8 bfr[4];
#pragma unroll
      for (int n = 0; n < 4; ++n) {
        const int row = wc * 64 + n * 16 + lr;
        bfr[n] = *(const bf16x8*)(cur + row * 256 + ((lg ^ lr) << 4));  // kk=0 chunk = lg
      }
#pragma unroll
      for (int m = 0; m < 4; ++m)
#pragma unroll
        for (int n = 0; n < 4; ++n)
          acc[m][n] = __builtin_amdgcn_mfma_f32_16x16x32_bf16(af[m][0], bfr[n], z4, 0, 0, 0);
    }
#pragma unroll
    for (int kk = 1; kk < 4; ++kk) {
      bf16x8 bfr[4];
#pragma unroll
      for (int n = 0; n < 4; ++n) {
        const int row = wc * 64 + n * 16 + lr;
        bfr[n] = *(const bf16x8*)(cur + row * 256 + (((kk * 4 + lg) ^ lr) << 4));
      }
#pragma unroll
      for (int m = 0; m < 4; ++m)
#pragma unroll
        for (int n = 0; n < 4; ++n)
          acc[m][n] = __builtin_amdgcn_mfma_f32_16x16x32_bf16(af[m][kk], bfr[n], acc[m][n], 0, 0, 0);
    }

    // exp + accumulate. C/D layout: col = lane&15 (within n-frag), row = lg*4 + reg.
    if (!between) {
#pragma unroll
      for (int m = 0; m < 4; ++m)
#pragma unroll
        for (int n = 0; n < 4; ++n)
#pragma unroll
          for (int r = 0; r < 4; ++r) rowp[m][r] += fexp2(acc[m][n][r]);
    } else {
      float colp[4];
#pragma unroll
      for (int n = 0; n < 4; ++n) colp[n] = 0.f;
#pragma unroll
      for (int m = 0; m < 4; ++m)
#pragma unroll
        for (int n = 0; n < 4; ++n) {
          float v0 = fexp2(acc[m][n][0]), v1 = fexp2(acc[m][n][1]);
          float v2 = fexp2(acc[m][n][2]), v3 = fexp2(acc[m][n][3]);
          rowp[m][0] += v0;
          rowp[m][1] += v1;
          rowp[m][2] += v2;
          rowp[m][3] += v3;
          colp[n] += (v0 + v1) + (v2 + v3);
        }
#pragma unroll
      for (int n = 0; n < 4; ++n) {  // per-tile col partial: reduce over lane-groups (rows)
        float c = colp[n];
        c += __shfl_xor(c, 16);
        c += __shfl_xor(c, 32);
        if (l < 16) atomicAdd(&colBet[(size_t)(j0 + t) * 128 + wc * 64 + n * 16 + l], c);
      }
    }
  }

  // ---- deferred row reduction: one shuffle-tree + atomic per row ----
  float* rowdst = between ? rowBet : rowRefl;
#pragma unroll
  for (int m = 0; m < 4; ++m)
#pragma unroll
    for (int r = 0; r < 4; ++r) {
      float s = rowp[m][r];
      s += __shfl_xor(s, 1);
      s += __shfl_xor(s, 2);
      s += __shfl_xor(s, 4);
      s += __shfl_xor(s, 8);
      if (lr == 0) atomicAdd(&rowdst[bi * 128 + wr * 64 + m * 16 + lg * 4 + r], s);
    }
}

// ---------- per-row loss (exact fp32 diagonals) ----------
__global__ void row_loss_kernel(const float* __restrict__ z1, const float* __restrict__ z2,
                                const float* __restrict__ rowRefl, const float* __restrict__ rowBet,
                                const float* __restrict__ colBet, float* __restrict__ rowLoss) {
  int gt = blockIdx.x * blockDim.x + threadIdx.x;
  int w = gt >> 6;  // one wave per row
  int l = threadIdx.x & 63;
  if (w >= N) return;
  float a0 = z1[w * D + l], a1 = z1[w * D + 64 + l];
  float b0 = z2[w * D + l], b1 = z2[w * D + 64 + l];
  float d11 = a0 * a0 + a1 * a1;  // |z1_i|^2
  float d12 = a0 * b0 + a1 * b1;  // z1_i . z2_i
#pragma unroll
  for (int mask = 1; mask < 64; mask <<= 1) {
    d11 += __shfl_xor(d11, mask);
    d12 += __shfl_xor(d12, mask);
  }
  if (l == 0) {
    float rdiag = fexp2(d11 * CEXP);  // exp(|z1_i|^2 / tau), exact fp32
    float denom1 = rowRefl[w] - rdiag + rowBet[w];
    float denom2 = rowRefl[w] - rdiag + colBet[w];
    // -log(pos) = -d12/tau = -2*d12 exactly (no exp/log roundtrip)
    rowLoss[w] = 0.5f * (logf(denom1) + logf(denom2)) - 2.0f * d12;
  }
}

__global__ void final_reduce_kernel(const float* __restrict__ rowLoss, float* __restrict__ out) {
  int g = blockIdx.x * 256 + threadIdx.x;  // grid: 32 blocks x 256 = 8192
  float s = rowLoss[g] * (1.0f / (float)N);
#pragma unroll
  for (int mask = 1; mask < 64; mask <<= 1) s += __shfl_xor(s, mask);
  if ((threadIdx.x & 63) == 0) atomicAdd(out, s);
}

extern "C" void kernel_launch(void* const* d_in, const int* in_sizes, int n_in,
                              void* d_out, int out_size, void* d_ws, size_t ws_size,
                              hipStream_t stream) {
  const float* z1 = (const float*)d_in[0];
  const float* z2 = (const float*)d_in[1];
  float* out = (float*)d_out;
  char* ws = (char*)d_ws;

  // workspace layout: z1b(2MB) | z2b(2MB) | rowRefl | rowBet | colBet | rowLoss
  u16* z1b = (u16*)ws;
  u16* z2b = (u16*)(ws + (size_t)N * D * 2);
  float* rowRefl = (float*)(ws + (size_t)2 * N * D * 2);
  float* rowBet = rowRefl + N;
  float* colBet = rowBet + N;
  float* rowLoss = colBet + N;

  convert_kernel<<<(N * D / 4) / 256, 256, 0, stream>>>((const float4*)z1, (const float4*)z2,
                                                        (uint2*)z1b, (uint2*)z2b);
  zero_kernel<<<(3 * N) / 256, 256, 0, stream>>>(rowRefl, out);  // rowRefl|rowBet|colBet contiguous
  gemm_kernel<<<512, 256, 0, stream>>>(z1b, z2b, rowRefl, rowBet, colBet);
  row_loss_kernel<<<(N * 64) / 256, 256, 0, stream>>>(z1, z2, rowRefl, rowBet, colBet, rowLoss);
  final_reduce_kernel<<<32, 256, 0, stream>>>(rowLoss, out);
}